// Round 3
// baseline (794.471 us; speedup 1.0000x reference)
//
#include <hip/hip_runtime.h>

#define Mdim 4096
#define Kdim 4096
#define Ndim 12288

typedef __bf16 bf16x8 __attribute__((ext_vector_type(8)));
typedef float f32x4 __attribute__((ext_vector_type(4)));
typedef unsigned short u16x8 __attribute__((ext_vector_type(8)));

__device__ __forceinline__ unsigned short f2bf(float f) {
    unsigned int u = __builtin_bit_cast(unsigned int, f);
    u += 0x7FFFu + ((u >> 16) & 1u);       // RNE
    return (unsigned short)(u >> 16);
}

typedef __attribute__((address_space(1))) void gvoid_t;
typedef __attribute__((address_space(3))) void lvoid_t;
__device__ __forceinline__ void gld16(const void* g, void* l) {
    // 16B per lane, LDS dest = wave-uniform base + lane*16
    __builtin_amdgcn_global_load_lds((gvoid_t*)g, (lvoid_t*)l, 16, 0, 0);
}

// ---------------------------------------------------------------------------
// Kernel 0: A fp32 -> bf16 (RNE), 8 elems/thread.
// ---------------------------------------------------------------------------
__global__ __launch_bounds__(256) void convert_a_kernel(
    const float* __restrict__ A, unsigned short* __restrict__ Ab)
{
    const size_t i = ((size_t)blockIdx.x * 256 + threadIdx.x) * 8;
    f32x4 v0 = *(const f32x4*)(A + i);
    f32x4 v1 = *(const f32x4*)(A + i + 4);
    u16x8 o;
#pragma unroll
    for (int j = 0; j < 4; ++j) { o[j] = f2bf(v0[j]); o[4 + j] = f2bf(v1[j]); }
    *(u16x8*)(Ab + i) = o;
}

// ---------------------------------------------------------------------------
// Kernel 1: dequant + K-permutation fold, output Wt[N][K] bf16 (B^T layout).
// Wt[n][j] = (nib(qw[k>>3][n], k&7) - 8) * (scode+1)^2 * smax[g], k=invperm[j].
// ---------------------------------------------------------------------------
__global__ __launch_bounds__(256) void dequant_permute_kernel(
    const int* __restrict__ qw,              // [K/8][N]
    const int* __restrict__ qs,              // [G][N/8]
    const float* __restrict__ qsm,           // [G] fp32
    const int* __restrict__ invperm,         // [K]
    unsigned short* __restrict__ Wt)         // [N][K] bf16 bits
{
    __shared__ int ks[64];
    __shared__ float tile[64 * 65];          // [n_local][j_local], pad->2-way only
    const int j0 = blockIdx.x * 64;
    const int n0 = blockIdx.y * 64;
    const int tid = threadIdx.x;
    if (tid < 64) ks[tid] = invperm[j0 + tid];
    __syncthreads();
    const int wave = tid >> 6, lane = tid & 63;
    const int n = n0 + lane;
#pragma unroll
    for (int t = 0; t < 16; ++t) {
        const int jl = wave * 16 + t;
        const int k = ks[jl];
        const int g = k >> 7;
        const int w = qw[(k >> 3) * Ndim + n];          // coalesced along n
        const int nib = (w >> ((k & 7) * 4)) & 0xF;
        const int sw = qs[g * (Ndim / 8) + (n >> 3)];
        const int sc = (sw >> ((n & 7) * 4)) & 0xF;
        const float scale = (float)((sc + 1) * (sc + 1)) * qsm[g];
        tile[lane * 65 + jl] = (float)(nib - 8) * scale;
    }
    __syncthreads();
#pragma unroll
    for (int cc = 0; cc < 2; ++cc) {
        const int c = tid + cc * 256;
        const int row = c >> 3, part = c & 7;
        const float* src = &tile[row * 65 + part * 8];
        u16x8 v;
#pragma unroll
        for (int i = 0; i < 8; ++i) v[i] = f2bf(src[i]);
        *(u16x8*)&Wt[(size_t)(n0 + row) * Kdim + j0 + part * 8] = v;
    }
}

// ---------------------------------------------------------------------------
// Kernel 2: bf16 GEMM, m97 structure + XOR-swizzled LDS.
// C[M][N] = A[M][K] * Wt[N][K]^T + bias.  128x128x32 tile, 4 waves,
// each wave 4x4 of 16x16x32 MFMA.
//
// LDS layout: 8 regions of 512 elems per tile; region r = rows [16r,16r+16).
// Physical slot s (16B chunk) within region holds (row = s>>2,
// c = (s&3) ^ ((s>>3)&3)).  global_load_lds writes lane l -> slot l, so the
// staging lane loads global chunk c = (l&3) ^ ((l>>3)&3) of row l>>2.
// Fragment read slot for (row,c): s = 4*row + (c ^ ((row>>1)&3)) -> bank-set
// = 4(row&1) + c^sigma spreads over all 8 sets => 2-way only (free, m136).
// ---------------------------------------------------------------------------
__global__ __launch_bounds__(256, 2) void gemm_bf16_kernel(
    const unsigned short* __restrict__ A,    // x [M][K] bf16 bits
    const unsigned short* __restrict__ Bt,   // Wt [N][K] bf16 bits
    const float* __restrict__ bias,          // [N] fp32
    float* __restrict__ C)                   // [M][N] fp32
{
    __shared__ __attribute__((aligned(16))) unsigned short As[128 * 32];
    __shared__ __attribute__((aligned(16))) unsigned short Bs[128 * 32];
    const int tid = threadIdx.x;
    const int wave = tid >> 6, lane = tid & 63;
    const int bn = blockIdx.x, bm = blockIdx.y;

    // staging: wave w fills rows [32w, 32w+32) = regions 2w, 2w+1.
    // lane l -> row 32w + (l>>2), swizzled chunk (l&3)^((l>>3)&3).
    const int srow = wave * 32 + (lane >> 2);
    const int skoff = (((lane & 3) ^ ((lane >> 3) & 3))) * 8;
    const unsigned short* Ag0 = A + (size_t)(bm * 128 + srow) * Kdim + skoff;
    const unsigned short* Ag1 = Ag0 + 16 * Kdim;
    const unsigned short* Bg0 = Bt + (size_t)(bn * 128 + srow) * Kdim + skoff;
    const unsigned short* Bg1 = Bg0 + 16 * Kdim;
    unsigned short* As0 = &As[(2 * wave) * 512];
    unsigned short* As1 = &As[(2 * wave + 1) * 512];
    unsigned short* Bs0 = &Bs[(2 * wave) * 512];
    unsigned short* Bs1 = &Bs[(2 * wave + 1) * 512];

    // compute: wave (wm,wn) owns 64x64 at (wm*64, wn*64)
    const int am = (wave >> 1) * 64, an = (wave & 1) * 64;
    // logical frag: row = lane&15 (within region), c = lane>>4.
    // physical slot = 4*row + (c ^ ((row>>1)&3)); elem offset = slot*8.
    const int rowl = lane & 15;
    const int cl = lane >> 4;
    const int fragoff = (4 * rowl + (cl ^ ((rowl >> 1) & 3))) * 8;
    const unsigned short* Ar = &As[(am >> 4) * 512 + fragoff];
    const unsigned short* Br = &Bs[(an >> 4) * 512 + fragoff];

    f32x4 acc[4][4];
    const f32x4 zero = {0.f, 0.f, 0.f, 0.f};
#pragma unroll
    for (int i = 0; i < 4; ++i)
#pragma unroll
        for (int j = 0; j < 4; ++j) acc[i][j] = zero;

    for (int kt = 0; kt < Kdim; kt += 32) {
        gld16(Ag0 + kt, As0);
        gld16(Ag1 + kt, As1);
        gld16(Bg0 + kt, Bs0);
        gld16(Bg1 + kt, Bs1);
        __syncthreads();
        bf16x8 af[4], bfr[4];
#pragma unroll
        for (int i = 0; i < 4; ++i) af[i] = *(const bf16x8*)(Ar + i * 512);
#pragma unroll
        for (int j = 0; j < 4; ++j) bfr[j] = *(const bf16x8*)(Br + j * 512);
#pragma unroll
        for (int i = 0; i < 4; ++i)
#pragma unroll
            for (int j = 0; j < 4; ++j)
                acc[i][j] = __builtin_amdgcn_mfma_f32_16x16x32_bf16(
                    af[i], bfr[j], acc[i][j], 0, 0, 0);
        __syncthreads();
    }

    // epilogue: C/D layout col = lane&15, row = (lane>>4)*4 + r  [m89-verified]
    const int colb = bn * 128 + an + (lane & 15);
    const int rowb = bm * 128 + am + (lane >> 4) * 4;
    float bj[4];
#pragma unroll
    for (int j = 0; j < 4; ++j) bj[j] = bias[colb + j * 16];
#pragma unroll
    for (int i = 0; i < 4; ++i)
#pragma unroll
        for (int r = 0; r < 4; ++r) {
            const size_t row = (size_t)(rowb + i * 16 + r);
#pragma unroll
            for (int j = 0; j < 4; ++j)
                C[row * Ndim + colb + j * 16] = acc[i][j][r] + bj[j];
        }
}

extern "C" void kernel_launch(void* const* d_in, const int* in_sizes, int n_in,
                              void* d_out, int out_size, void* d_ws, size_t ws_size,
                              hipStream_t stream) {
    const float* input   = (const float*)d_in[0];   // [M][K] fp32 (fp16 promoted)
    const int*   qw      = (const int*)d_in[1];     // [K/8][N]
    const int*   qs      = (const int*)d_in[2];     // [G][N/8]
    const float* qsm     = (const float*)d_in[3];   // [G] fp32
    const int*   invperm = (const int*)d_in[4];     // [K]
    const float* bias    = (const float*)d_in[5];   // [N] fp32 (zeros)
    float*       out     = (float*)d_out;           // [M][N] fp32

    unsigned short* Ab = (unsigned short*)d_ws;                      // 32 MiB
    unsigned short* Wt = (unsigned short*)((char*)d_ws + ((size_t)Mdim * Kdim * 2)); // 96 MiB

    convert_a_kernel<<<(Mdim * Kdim) / (256 * 8), 256, 0, stream>>>(input, Ab);
    dequant_permute_kernel<<<dim3(Kdim / 64, Ndim / 64), 256, 0, stream>>>(
        qw, qs, qsm, invperm, Wt);
    gemm_bf16_kernel<<<dim3(Ndim / 128, Mdim / 128), 256, 0, stream>>>(
        Ab, Wt, bias, out);
}

// Round 4
// 766.928 us; speedup vs baseline: 1.0359x; 1.0359x over previous
//
#include <hip/hip_runtime.h>

#define Mdim 4096
#define Kdim 4096
#define Ndim 12288

typedef __bf16 bf16x8 __attribute__((ext_vector_type(8)));
typedef float f32x4 __attribute__((ext_vector_type(4)));
typedef unsigned short u16x8 __attribute__((ext_vector_type(8)));
typedef int i32x4 __attribute__((ext_vector_type(4)));

__device__ __forceinline__ unsigned short f2bf(float f) {
    unsigned int u = __builtin_bit_cast(unsigned int, f);
    u += 0x7FFFu + ((u >> 16) & 1u);       // RNE
    return (unsigned short)(u >> 16);
}

typedef __attribute__((address_space(1))) void gvoid_t;
typedef __attribute__((address_space(3))) void lvoid_t;
__device__ __forceinline__ void gld16(const void* g, void* l) {
    // 16B per lane, LDS dest = wave-uniform base + lane*16
    __builtin_amdgcn_global_load_lds((gvoid_t*)g, (lvoid_t*)l, 16, 0, 0);
}

// ---------------------------------------------------------------------------
// Kernel 0: A fp32 -> bf16 with K-permutation folded in (scatter by invperm:
// Ab[m][invperm[i]] = A[m][i], equivalent to Ab[m][j] = A[m][perm[j]]).
// Scatter happens in a per-row LDS buffer (row = 16 KB fp32 -> 8 KB bf16),
// so all global reads AND writes stay fully coalesced. 2 rows per block.
// ---------------------------------------------------------------------------
__global__ __launch_bounds__(256) void permute_convert_a_kernel(
    const float* __restrict__ A, const int* __restrict__ invperm,
    unsigned short* __restrict__ Ab)
{
    __shared__ unsigned short rowbuf[2][Kdim];
    const int tid = threadIdx.x;
    const int m0 = blockIdx.x * 2;
#pragma unroll
    for (int c = 0; c < 4; ++c) {
        const int i = (c * 256 + tid) * 4;
        const i32x4 ip = *(const i32x4*)&invperm[i];
        const f32x4 v0 = *(const f32x4*)&A[(size_t)m0 * Kdim + i];
        const f32x4 v1 = *(const f32x4*)&A[(size_t)(m0 + 1) * Kdim + i];
#pragma unroll
        for (int u = 0; u < 4; ++u) {
            rowbuf[0][ip[u]] = f2bf(v0[u]);
            rowbuf[1][ip[u]] = f2bf(v1[u]);
        }
    }
    __syncthreads();
#pragma unroll
    for (int r = 0; r < 2; ++r)
#pragma unroll
        for (int c = 0; c < 2; ++c) {
            const int j = (c * 256 + tid) * 8;
            const u16x8 o = *(const u16x8*)&rowbuf[r][j];
            *(u16x8*)&Ab[(size_t)(m0 + r) * Kdim + j] = o;
        }
}

// ---------------------------------------------------------------------------
// Kernel 1: dequant in NATURAL k-order (no permutation -> zero overfetch).
// Wt[n][k] = (nib(qw[k>>3][n], k&7) - 8) * (scode(g,n)+1)^2 * smax[g].
// Block tile 64k x 64n; each qw word read once, all 8 nibbles used
// (8 consecutive k = contiguous 16B in the Wt row). g uniform per block.
// LDS transpose tile stride 72 halves (144 B): 16B-aligned b128 ops.
// ---------------------------------------------------------------------------
__global__ __launch_bounds__(256) void dequant_kernel(
    const int* __restrict__ qw,              // [K/8][N]
    const int* __restrict__ qs,              // [G][N/8]
    const float* __restrict__ qsm,           // [G] fp32
    unsigned short* __restrict__ Wt)         // [N][K] bf16 bits
{
    __shared__ unsigned short tile[64 * 72];
    const int k0 = blockIdx.x * 64;
    const int n0 = blockIdx.y * 64;
    const int g = k0 >> 7;                    // 64-tile lies in one 128-group
    const int tid = threadIdx.x;
    const int n_l = tid & 63;
    const int kb_l = tid >> 6;                // 0..3
    const int n = n0 + n_l;
    const int sw = qs[g * (Ndim / 8) + (n >> 3)];
    const int sc = (sw >> ((n & 7) * 4)) & 0xF;
    const float scale = (float)((sc + 1) * (sc + 1)) * qsm[g];
#pragma unroll
    for (int ii = 0; ii < 2; ++ii) {
        const int kb = kb_l + ii * 4;         // 0..7 (k = k0 + kb*8 + u)
        const int w = qw[(size_t)(k0 / 8 + kb) * Ndim + n];   // coalesced, used fully
        u16x8 o;
#pragma unroll
        for (int u = 0; u < 8; ++u)
            o[u] = f2bf((float)(((w >> (4 * u)) & 0xF) - 8) * scale);
        *(u16x8*)&tile[n_l * 72 + kb * 8] = o;
    }
    __syncthreads();
#pragma unroll
    for (int cc = 0; cc < 2; ++cc) {
        const int c = tid + cc * 256;
        const int row = c >> 3, part = c & 7;
        const u16x8 v = *(const u16x8*)&tile[row * 72 + part * 8];
        *(u16x8*)&Wt[(size_t)(n0 + row) * Kdim + k0 + part * 8] = v;
    }
}

// ---------------------------------------------------------------------------
// Kernel 2: bf16 GEMM, m97 structure + XOR-swizzled LDS (0 bank conflicts).
// C[M][N] = Ab[M][K] * Wt[N][K]^T + bias.  128x128x32 tile, 4 waves,
// each wave 4x4 of 16x16x32 MFMA.  (unchanged from round 3)
// ---------------------------------------------------------------------------
__global__ __launch_bounds__(256, 2) void gemm_bf16_kernel(
    const unsigned short* __restrict__ A,    // x-permuted [M][K] bf16 bits
    const unsigned short* __restrict__ Bt,   // Wt [N][K] bf16 bits
    const float* __restrict__ bias,          // [N] fp32
    float* __restrict__ C)                   // [M][N] fp32
{
    __shared__ __attribute__((aligned(16))) unsigned short As[128 * 32];
    __shared__ __attribute__((aligned(16))) unsigned short Bs[128 * 32];
    const int tid = threadIdx.x;
    const int wave = tid >> 6, lane = tid & 63;
    const int bn = blockIdx.x, bm = blockIdx.y;

    // staging: wave w fills rows [32w, 32w+32) = regions 2w, 2w+1.
    // lane l -> row 32w + (l>>2), swizzled chunk (l&3)^((l>>3)&3).
    const int srow = wave * 32 + (lane >> 2);
    const int skoff = (((lane & 3) ^ ((lane >> 3) & 3))) * 8;
    const unsigned short* Ag0 = A + (size_t)(bm * 128 + srow) * Kdim + skoff;
    const unsigned short* Ag1 = Ag0 + 16 * Kdim;
    const unsigned short* Bg0 = Bt + (size_t)(bn * 128 + srow) * Kdim + skoff;
    const unsigned short* Bg1 = Bg0 + 16 * Kdim;
    unsigned short* As0 = &As[(2 * wave) * 512];
    unsigned short* As1 = &As[(2 * wave + 1) * 512];
    unsigned short* Bs0 = &Bs[(2 * wave) * 512];
    unsigned short* Bs1 = &Bs[(2 * wave + 1) * 512];

    // compute: wave (wm,wn) owns 64x64 at (wm*64, wn*64)
    const int am = (wave >> 1) * 64, an = (wave & 1) * 64;
    // logical frag: row = lane&15 (within region), c = lane>>4.
    // physical slot = 4*row + (c ^ ((row>>1)&3)); elem offset = slot*8.
    const int rowl = lane & 15;
    const int cl = lane >> 4;
    const int fragoff = (4 * rowl + (cl ^ ((rowl >> 1) & 3))) * 8;
    const unsigned short* Ar = &As[(am >> 4) * 512 + fragoff];
    const unsigned short* Br = &Bs[(an >> 4) * 512 + fragoff];

    f32x4 acc[4][4];
    const f32x4 zero = {0.f, 0.f, 0.f, 0.f};
#pragma unroll
    for (int i = 0; i < 4; ++i)
#pragma unroll
        for (int j = 0; j < 4; ++j) acc[i][j] = zero;

    for (int kt = 0; kt < Kdim; kt += 32) {
        gld16(Ag0 + kt, As0);
        gld16(Ag1 + kt, As1);
        gld16(Bg0 + kt, Bs0);
        gld16(Bg1 + kt, Bs1);
        __syncthreads();
        bf16x8 af[4], bfr[4];
#pragma unroll
        for (int i = 0; i < 4; ++i) af[i] = *(const bf16x8*)(Ar + i * 512);
#pragma unroll
        for (int j = 0; j < 4; ++j) bfr[j] = *(const bf16x8*)(Br + j * 512);
#pragma unroll
        for (int i = 0; i < 4; ++i)
#pragma unroll
            for (int j = 0; j < 4; ++j)
                acc[i][j] = __builtin_amdgcn_mfma_f32_16x16x32_bf16(
                    af[i], bfr[j], acc[i][j], 0, 0, 0);
        __syncthreads();
    }

    // epilogue: C/D layout col = lane&15, row = (lane>>4)*4 + r  [m89-verified]
    const int colb = bn * 128 + an + (lane & 15);
    const int rowb = bm * 128 + am + (lane >> 4) * 4;
    float bj[4];
#pragma unroll
    for (int j = 0; j < 4; ++j) bj[j] = bias[colb + j * 16];
#pragma unroll
    for (int i = 0; i < 4; ++i)
#pragma unroll
        for (int r = 0; r < 4; ++r) {
            const size_t row = (size_t)(rowb + i * 16 + r);
#pragma unroll
            for (int j = 0; j < 4; ++j)
                C[row * Ndim + colb + j * 16] = acc[i][j][r] + bj[j];
        }
}

extern "C" void kernel_launch(void* const* d_in, const int* in_sizes, int n_in,
                              void* d_out, int out_size, void* d_ws, size_t ws_size,
                              hipStream_t stream) {
    const float* input   = (const float*)d_in[0];   // [M][K] fp32 (fp16 promoted)
    const int*   qw      = (const int*)d_in[1];     // [K/8][N]
    const int*   qs      = (const int*)d_in[2];     // [G][N/8]
    const float* qsm     = (const float*)d_in[3];   // [G] fp32
    const int*   invperm = (const int*)d_in[4];     // [K]
    const float* bias    = (const float*)d_in[5];   // [N] fp32 (zeros)
    float*       out     = (float*)d_out;           // [M][N] fp32

    unsigned short* Ab = (unsigned short*)d_ws;                      // 32 MiB
    unsigned short* Wt = (unsigned short*)((char*)d_ws + ((size_t)Mdim * Kdim * 2)); // 96 MiB

    permute_convert_a_kernel<<<Mdim / 2, 256, 0, stream>>>(input, invperm, Ab);
    dequant_kernel<<<dim3(Kdim / 64, Ndim / 64), 256, 0, stream>>>(qw, qs, qsm, Wt);
    gemm_bf16_kernel<<<dim3(Ndim / 128, Mdim / 128), 256, 0, stream>>>(
        Ab, Wt, bias, out);
}